// Round 1
// baseline (365.251 us; speedup 1.0000x reference)
//
#include <hip/hip_runtime.h>
#include <hip/hip_bf16.h>

// Problem constants (from reference)
#define N_NODES 50000
#define N_REL   8
#define DIM     128      // IN_DIM == HID == 128
#define N_EDGES 800000
#define N_TRIP  100000
#define NDBLK   196                  // ceil(50000/256) dst blocks
#define NB2     (N_REL * NDBLK)      // 1568 rel-major buckets
#define CAP2    1024                 // slack per bucket (mean 510, std ~23)
#define NOFF    (N_REL * N_NODES + 1)

typedef __attribute__((ext_vector_type(8))) short bf16x8;
typedef __attribute__((ext_vector_type(4))) float f32x4;

static __device__ __forceinline__ unsigned short f2b(float f) {
    __hip_bfloat16 h = __float2bfloat16(f);
    return *reinterpret_cast<unsigned short*>(&h);
}
static __device__ __forceinline__ float blo(unsigned int u) {
    return __uint_as_float(u << 16);
}
static __device__ __forceinline__ float bhi(unsigned int u) {
    return __uint_as_float(u & 0xffff0000u);
}
// XOR-swizzled LDS offset (units: shorts): chunk c of row n -> slot (c ^ (n&7))
static __device__ __forceinline__ int lds_off(int row, int chunk) {
    return (row * 16 + (chunk ^ (row & 7))) * 8;
}

// ---------------------------------------------------------------------------
// bucket_scatter: bin edges by (rel, dst>>8) into fixed-capacity slack regions.
// packed word: src[0:16) | dstLow[16:24)
__global__ __launch_bounds__(256) void bucket_scatter(
        const int* __restrict__ edge_index,
        const int* __restrict__ edge_type,
        int* __restrict__ gcnt,
        unsigned int* __restrict__ slack) {
    __shared__ int hist[NB2];
    __shared__ int cur[NB2];
    int tid = threadIdx.x;
    for (int i = tid; i < NB2; i += 256) hist[i] = 0;
    __syncthreads();
    int base = blockIdx.x * 4096;
    unsigned int w[16];
    int bk[16];
    #pragma unroll
    for (int i = 0; i < 16; ++i) {
        int e = base + i * 256 + tid;
        if (e < N_EDGES) {
            int src = edge_index[e];
            int dst = edge_index[N_EDGES + e];
            int r = edge_type[e];
            w[i] = (unsigned int)src | ((unsigned int)(dst & 255) << 16);
            bk[i] = r * NDBLK + (dst >> 8);
            atomicAdd(&hist[bk[i]], 1);
        } else {
            bk[i] = -1;
        }
    }
    __syncthreads();
    for (int i = tid; i < NB2; i += 256)
        cur[i] = atomicAdd(&gcnt[i], hist[i]);
    __syncthreads();
    #pragma unroll
    for (int i = 0; i < 16; ++i) {
        if (bk[i] >= 0) {
            int p = atomicAdd(&cur[bk[i]], 1);
            if (p < CAP2) slack[(size_t)bk[i] * CAP2 + p] = w[i];
        }
    }
}

// ---------------------------------------------------------------------------
// bucket_scan: exclusive scan of 1568 bucket counts (blocked, 8/thread);
// also set the flat-offset sentinel.
__global__ void bucket_scan(const int* __restrict__ gcnt,
                            int* __restrict__ gbase,
                            int* __restrict__ offR) {
    __shared__ int sh[256];
    int t = threadIdx.x;
    int c[8];
    int s = 0;
    #pragma unroll
    for (int j = 0; j < 8; ++j) {
        int idx = t * 8 + j;
        int v = (idx < NB2) ? gcnt[idx] : 0;
        c[j] = v; s += v;
    }
    sh[t] = s;
    __syncthreads();
    #pragma unroll
    for (int off = 1; off < 256; off <<= 1) {
        int x = (t >= off) ? sh[t - off] : 0;
        __syncthreads();
        sh[t] += x;
        __syncthreads();
    }
    int ex = sh[t] - s;
    #pragma unroll
    for (int j = 0; j < 8; ++j) {
        int idx = t * 8 + j;
        if (idx < NB2) gbase[idx] = ex;
        ex += c[j];
    }
    if (t == 0) offR[N_REL * N_NODES] = N_EDGES;
}

// ---------------------------------------------------------------------------
// bucket_sort: one block per (rel, 256-dst) bucket. LDS counting sort over
// 256 dstLow bins. Writes sorted_pack (src | dstLow<<16) and flat offsets
// offR[r*N + dst] (monotone over the rel-major global order).
__global__ __launch_bounds__(256) void bucket_sort(
        const unsigned int* __restrict__ slack,
        const int* __restrict__ gcnt,
        const int* __restrict__ gbase,
        unsigned int* __restrict__ spack,
        int* __restrict__ offR) {
    __shared__ unsigned int ebuf[CAP2];   // 4 KB
    __shared__ unsigned int obuf[CAP2];   // 4 KB
    __shared__ int hist[256];             // cursor after scan
    __shared__ int excl[256];
    __shared__ int sh[256];
    int b = blockIdx.x, t = threadIdx.x;
    int r = b / NDBLK, dblk = b % NDBLK;
    int n = gcnt[b]; if (n > CAP2) n = CAP2;
    int bb = gbase[b];
    for (int i = t; i < n; i += 256) ebuf[i] = slack[(size_t)b * CAP2 + i];
    hist[t] = 0;
    __syncthreads();
    for (int i = t; i < n; i += 256)
        atomicAdd(&hist[(ebuf[i] >> 16) & 255], 1);
    __syncthreads();
    int c = hist[t];
    sh[t] = c;
    __syncthreads();
    #pragma unroll
    for (int off = 1; off < 256; off <<= 1) {
        int x = (t >= off) ? sh[t - off] : 0;
        __syncthreads();
        sh[t] += x;
        __syncthreads();
    }
    int ex = sh[t] - c;
    excl[t] = ex;
    hist[t] = ex;   // reuse as cursor
    __syncthreads();
    for (int i = t; i < n; i += 256) {
        unsigned int w = ebuf[i];
        int p = atomicAdd(&hist[(w >> 16) & 255], 1);
        obuf[p] = w;
    }
    __syncthreads();
    for (int i = t; i < n; i += 256) spack[bb + i] = obuf[i];
    int dst = dblk * 256 + t;
    if (dst < N_NODES) offR[r * N_NODES + dst] = bb + excl[t];
}

// ---------------------------------------------------------------------------
// cvt_emb: fp32 -> bf16, 2 elems/thread (packed)
__global__ void cvt_emb_kernel(const float* __restrict__ src,
                               unsigned short* __restrict__ dst) {
    int i = blockIdx.x * blockDim.x + threadIdx.x;
    const int npair = N_NODES * DIM / 2;
    if (i >= npair) return;
    float2 v = ((const float2*)src)[i];
    unsigned int p = (unsigned int)f2b(v.x) | ((unsigned int)f2b(v.y) << 16);
    ((unsigned int*)dst)[i] = p;
}

// ---------------------------------------------------------------------------
// cvt_w2: Wt2[s][n][k] bf16 for both layers; s=0 -> root, s>=1 -> W_{s-1}.
__global__ void cvt_w2_kernel(const float* __restrict__ root0,
                              const float* __restrict__ W0,
                              const float* __restrict__ root1,
                              const float* __restrict__ W1,
                              unsigned short* __restrict__ Wt2a,
                              unsigned short* __restrict__ Wt2b) {
    int s = blockIdx.x;        // 0..8
    int n = blockIdx.y;        // 0..127
    int k = threadIdx.x;       // 0..127
    const float* root = blockIdx.z ? root1 : root0;
    const float* W    = blockIdx.z ? W1 : W0;
    unsigned short* Wt2 = blockIdx.z ? Wt2b : Wt2a;
    float v = (s == 0) ? root[k * 128 + n]
                       : W[((size_t)(s - 1) * 128 + k) * 128 + n];
    Wt2[((size_t)s * 128 + n) * 128 + k] = f2b(v);
}

// ---------------------------------------------------------------------------
// rgcn_fused: one full RGCN layer per launch. Block = 64-dst tile, 4 waves.
// For each rel r: each wave streams the sorted edges of its 16 dsts,
// accumulates the fp32 mean of raw h[src] rows (2 dims/lane), flush-on-dst-
// change writes the bf16 mean row into a 16 KB XOR-swizzled LDS tile; then
// all waves MFMA the tile against W_{r} (K=128), accumulating across all 9
// slots (slot 0 = root, A-frags straight from global h) in registers.
// Epilogue: +bias, relu, bf16 store. No 9-slot Y materialization.
__global__ __launch_bounds__(256) void rgcn_fused(
        const unsigned short* __restrict__ hb,    // N x 128 bf16
        const unsigned short* __restrict__ Wt2,   // 9 x 128(n) x 128(k) bf16
        const float* __restrict__ bias,           // 128
        const int* __restrict__ offR,             // 8*N + 1 flat offsets
        const unsigned int* __restrict__ spack,   // src | dstLow<<16
        unsigned short* __restrict__ hout) {      // N x 128 bf16
    __shared__ unsigned short Mbuf[64 * 16 * 8];  // 16 KB swizzled mean tile
    unsigned int* Mb32 = (unsigned int*)Mbuf;
    const unsigned int* hb32 = (const unsigned int*)hb;

    int tid = threadIdx.x;
    int wid = tid >> 6, lane = tid & 63;
    int quad = lane >> 4, l16 = lane & 15;
    int t0 = blockIdx.x * 64;
    int col0w = wid * 32;

    f32x4 acc[4][2];
    #pragma unroll
    for (int mi = 0; mi < 4; ++mi)
        #pragma unroll
        for (int ni = 0; ni < 2; ++ni)
            acc[mi][ni] = (f32x4){0.f, 0.f, 0.f, 0.f};

    // ---- slot 0: root transform, A-frags direct from global h ----
    {
        const unsigned short* Wp = Wt2 + ((size_t)(col0w + l16)) * DIM + quad * 8;
        bf16x8 bf[2][4];
        #pragma unroll
        for (int ni = 0; ni < 2; ++ni)
            #pragma unroll
            for (int kk = 0; kk < 4; ++kk)
                bf[ni][kk] = *(const bf16x8*)(Wp + (ni * 16) * DIM + kk * 32);
        #pragma unroll
        for (int kk = 0; kk < 4; ++kk)
            #pragma unroll
            for (int mi = 0; mi < 4; ++mi) {
                int grow = t0 + mi * 16 + l16;
                if (grow >= N_NODES) grow = N_NODES - 1;
                bf16x8 af = *(const bf16x8*)(hb + (size_t)grow * DIM + kk * 32 + quad * 8);
                #pragma unroll
                for (int ni = 0; ni < 2; ++ni)
                    acc[mi][ni] = __builtin_amdgcn_mfma_f32_16x16x32_bf16(
                        af, bf[ni][kk], acc[mi][ni], 0, 0, 0);
            }
    }

    // ---- relation slots ----
    for (int r = 0; r < N_REL; ++r) {
        // B-frags for slot 1+r issued early (L2-hot, hides under aggregation)
        const unsigned short* Wp = Wt2 + ((size_t)(1 + r) * DIM + col0w + l16) * DIM + quad * 8;
        bf16x8 bf[2][4];
        #pragma unroll
        for (int ni = 0; ni < 2; ++ni)
            #pragma unroll
            for (int kk = 0; kk < 4; ++kk)
                bf[ni][kk] = *(const bf16x8*)(Wp + (ni * 16) * DIM + kk * 32);

        // aggregate mean rows for this wave's 16 dsts
        int d0 = t0 + wid * 16;
        int ia = d0 < N_NODES ? d0 : N_NODES;
        int ib = (d0 + 16) < N_NODES ? (d0 + 16) : N_NODES;
        int beg = offR[r * N_NODES + ia];
        int end = offR[r * N_NODES + ib];
        unsigned int flushed = 0;
        float a0 = 0.f, a1 = 0.f;
        int curd = -1, cnt = 0;
        for (int base = beg; base < end; base += 64) {
            int m = end - base; if (m > 64) m = 64;
            unsigned int pk = 0;
            if (lane < m) pk = spack[base + lane];
            for (int j = 0; j < m; j += 8) {
                int bc = m - j; if (bc > 8) bc = 8;
                unsigned int pp[8], vv[8];
                #pragma unroll
                for (int q = 0; q < 8; ++q)
                    if (q < bc) pp[q] = (unsigned int)__shfl((int)pk, j + q, 64);
                #pragma unroll
                for (int q = 0; q < 8; ++q)
                    if (q < bc) vv[q] = hb32[(size_t)(pp[q] & 0xffffu) * 64 + lane];
                #pragma unroll
                for (int q = 0; q < 8; ++q) {
                    if (q < bc) {
                        int dl = (int)((pp[q] >> 16) & 63u);   // dst & 63 = tile row
                        float x0 = blo(vv[q]), x1 = bhi(vv[q]);
                        if (dl != curd) {                       // wave-uniform branch
                            if (curd >= 0) {
                                float inv = __builtin_amdgcn_rcpf((float)cnt);
                                Mb32[(curd * 16 + ((lane >> 2) ^ (curd & 7))) * 4 + (lane & 3)] =
                                    (unsigned int)f2b(a0 * inv) |
                                    ((unsigned int)f2b(a1 * inv) << 16);
                                flushed |= 1u << (curd & 15);
                            }
                            curd = dl; a0 = x0; a1 = x1; cnt = 1;
                        } else {
                            a0 += x0; a1 += x1; ++cnt;
                        }
                    }
                }
            }
        }
        if (curd >= 0) {
            float inv = __builtin_amdgcn_rcpf((float)cnt);
            Mb32[(curd * 16 + ((lane >> 2) ^ (curd & 7))) * 4 + (lane & 3)] =
                (unsigned int)f2b(a0 * inv) | ((unsigned int)f2b(a1 * inv) << 16);
            flushed |= 1u << (curd & 15);
        }
        // zero this wave's rows that had no edges (empty segments -> mean 0)
        #pragma unroll
        for (int i = 0; i < 16; ++i) {
            if (!((flushed >> i) & 1u)) {
                int row = wid * 16 + i;
                Mb32[(row * 16 + ((lane >> 2) ^ (row & 7))) * 4 + (lane & 3)] = 0u;
            }
        }
        __syncthreads();

        // MFMA slot 1+r: A-frags from swizzled LDS mean tile
        #pragma unroll
        for (int kk = 0; kk < 4; ++kk)
            #pragma unroll
            for (int mi = 0; mi < 4; ++mi) {
                bf16x8 af = *(const bf16x8*)&Mbuf[lds_off(mi * 16 + l16, kk * 4 + quad)];
                #pragma unroll
                for (int ni = 0; ni < 2; ++ni)
                    acc[mi][ni] = __builtin_amdgcn_mfma_f32_16x16x32_bf16(
                        af, bf[ni][kk], acc[mi][ni], 0, 0, 0);
            }
        __syncthreads();   // protect Mbuf before next rel's writes
    }

    // ---- epilogue: bias + relu + bf16 store ----
    // C/D layout: col = lane&15, row = (lane>>4)*4 + reg
    #pragma unroll
    for (int ni = 0; ni < 2; ++ni) {
        int gc = col0w + ni * 16 + l16;
        float bv = bias[gc];
        #pragma unroll
        for (int mi = 0; mi < 4; ++mi)
            #pragma unroll
            for (int rr = 0; rr < 4; ++rr) {
                int grow = t0 + mi * 16 + quad * 4 + rr;
                if (grow < N_NODES)
                    hout[(size_t)grow * DIM + gc] = f2b(fmaxf(acc[mi][ni][rr] + bv, 0.f));
            }
    }
}

// ---------------------------------------------------------------------------
// score: out[t] = sum_d h[head,d]*rel_emb[rel,d]*h[tail,d]  (h in bf16)
__global__ void score_kernel(const unsigned short* __restrict__ hb,
                             const float* __restrict__ rel_emb,
                             const int* __restrict__ head,
                             const int* __restrict__ rel,
                             const int* __restrict__ tail,
                             float* __restrict__ out) {
    int t = blockIdx.x * 4 + (threadIdx.x >> 6);
    if (t >= N_TRIP) return;
    int lane = threadIdx.x & 63;
    unsigned int ph = ((const unsigned int*)(hb + (size_t)head[t] * DIM))[lane];
    unsigned int pt = ((const unsigned int*)(hb + (size_t)tail[t] * DIM))[lane];
    float2 rr = ((const float2*)(rel_emb + (size_t)rel[t] * DIM))[lane];
    float s = blo(ph) * rr.x * blo(pt) + bhi(ph) * rr.y * bhi(pt);
    #pragma unroll
    for (int off = 32; off; off >>= 1) s += __shfl_xor(s, off, 64);
    if (lane == 0) out[t] = s;
}

// ---------------------------------------------------------------------------
extern "C" void kernel_launch(void* const* d_in, const int* in_sizes, int n_in,
                              void* d_out, int out_size, void* d_ws, size_t ws_size,
                              hipStream_t stream) {
    const float* emb     = (const float*)d_in[0];
    const float* W0      = (const float*)d_in[1];
    const float* root0   = (const float*)d_in[2];
    const float* b0      = (const float*)d_in[3];
    const float* W1      = (const float*)d_in[4];
    const float* root1   = (const float*)d_in[5];
    const float* b1      = (const float*)d_in[6];
    const float* rel_emb = (const float*)d_in[7];
    const int* edge_index = (const int*)d_in[8];
    const int* edge_type  = (const int*)d_in[9];
    const int* head_idx   = (const int*)d_in[10];
    const int* rel_idx    = (const int*)d_in[11];
    const int* tail_idx   = (const int*)d_in[12];
    float* out = (float*)d_out;

    // workspace layout (~52 MB, all disjoint, 16B-aligned chunks first):
    char* p = (char*)d_ws;
    size_t hb_bytes  = (size_t)N_NODES * DIM * sizeof(unsigned short);     // 12.8 MB
    size_t wt2_bytes = (size_t)9 * 128 * 128 * sizeof(unsigned short);     // 294912 B
    unsigned short* embb = (unsigned short*)p; p += hb_bytes;
    unsigned short* h1b  = (unsigned short*)p; p += hb_bytes;
    unsigned short* h2b  = (unsigned short*)p; p += hb_bytes;
    unsigned short* Wt2a = (unsigned short*)p; p += wt2_bytes;
    unsigned short* Wt2b = (unsigned short*)p; p += wt2_bytes;
    unsigned int* spack = (unsigned int*)p;   p += (size_t)N_EDGES * sizeof(unsigned int);
    unsigned int* slack = (unsigned int*)p;   p += (size_t)NB2 * CAP2 * sizeof(unsigned int);
    int* gcnt  = (int*)p;  p += (size_t)NB2 * sizeof(int);
    int* gbase = (int*)p;  p += (size_t)NB2 * sizeof(int);
    int* offR  = (int*)p;  p += (size_t)NOFF * sizeof(int);
    (void)ws_size; (void)in_sizes; (void)n_in; (void)out_size;

    dim3 blk256(256);

    // ---- 2-pass bucket sort of edges, rel-major: key = (rel, dst) ----
    hipMemsetAsync(gcnt, 0, (size_t)NB2 * sizeof(int), stream);
    bucket_scatter<<<(N_EDGES + 4095) / 4096, blk256, 0, stream>>>(edge_index, edge_type,
                                                                   gcnt, slack);
    bucket_scan<<<1, 256, 0, stream>>>(gcnt, gbase, offR);
    bucket_sort<<<NB2, blk256, 0, stream>>>(slack, gcnt, gbase, spack, offR);

    // ---- precision conversions ----
    cvt_emb_kernel<<<(N_NODES * DIM / 2 + 255) / 256, blk256, 0, stream>>>(emb, embb);
    cvt_w2_kernel<<<dim3(9, 128, 2), 128, 0, stream>>>(root0, W0, root1, W1, Wt2a, Wt2b);

    int fgrid = (N_NODES + 63) / 64;   // 782 blocks

    // ---- fused layers: aggregate raw means in LDS, transform via MFMA ----
    rgcn_fused<<<fgrid, blk256, 0, stream>>>(embb, Wt2a, b0, offR, spack, h1b);
    rgcn_fused<<<fgrid, blk256, 0, stream>>>(h1b, Wt2b, b1, offR, spack, h2b);

    // ---- score ----
    score_kernel<<<(N_TRIP + 3) / 4, blk256, 0, stream>>>(h2b, rel_emb, head_idx, rel_idx,
                                                          tail_idx, out);
}